// Round 1
// baseline (1104.368 us; speedup 1.0000x reference)
//
#include <hip/hip_runtime.h>
#include <math.h>

namespace {

constexpr int kB = 128;
constexpr int kS = 1024;
constexpr int kD = 64;
constexpr int kTK = 64;            // key-tile size
constexpr int kRowsPerWave = 8;
constexpr int kWaves = 4;
constexpr int kRowsPerBlock = kRowsPerWave * kWaves;  // 32
constexpr int kThreads = 64 * kWaves;                 // 256

__device__ __forceinline__ float wave_max64(float x) {
#pragma unroll
  for (int m = 32; m >= 1; m >>= 1) x = fmaxf(x, __shfl_xor(x, m, 64));
  return x;
}

__device__ __forceinline__ float wave_sum64(float x) {
#pragma unroll
  for (int m = 32; m >= 1; m >>= 1) x += __shfl_xor(x, m, 64);
  return x;
}

// Broadcast lane `l`'s value of x to all lanes, landing in an SGPR so the
// consuming v_fmac uses it as its one scalar operand.
__device__ __forceinline__ float lane_bcast(float x, int l) {
  return __uint_as_float(__builtin_amdgcn_readlane(__float_as_uint(x), l));
}

__global__ __launch_bounds__(kThreads, 2)
void fa_fp32_kernel(const float* __restrict__ q, const float* __restrict__ k,
                    const float* __restrict__ v, float* __restrict__ out) {
  // kT[d][j]: QK phase reads kT[d][lane] -> bank = lane%32, conflict-free.
  // vS[j][d]: PV phase reads vS[j][lane] -> bank = lane%32, conflict-free.
  __shared__ float kT[kD][kTK];
  __shared__ float vS[kTK][kD];

  const int tid  = threadIdx.x;
  const int lane = tid & 63;
  // readfirstlane makes the wave id compiler-uniform -> q row pointers become
  // SGPR addresses -> q scalars arrive via s_load (scalar pipe, free).
  const int w = __builtin_amdgcn_readfirstlane(tid >> 6);

  const int qt = blockIdx.x;   // q-row tile: 0..31
  const int b  = blockIdx.y;   // batch: 0..127

  const float* qb = q + (size_t)b * kS * kD;
  const float* kb = k + (size_t)b * kS * kD;
  const float* vb = v + (size_t)b * kS * kD;
  float*       ob = out + (size_t)b * kS * kD;

  const int row0 = qt * kRowsPerBlock + w * kRowsPerWave;

  // Online-softmax state. o_i: lane holds dim `lane` of row i's accumulator.
  float m_i[kRowsPerWave], l_i[kRowsPerWave], o_i[kRowsPerWave];
#pragma unroll
  for (int i = 0; i < kRowsPerWave; ++i) {
    m_i[i] = -INFINITY;
    l_i[i] = 0.f;
    o_i[i] = 0.f;
  }

  for (int kt = 0; kt < kS / kTK; ++kt) {
    __syncthreads();
    // ---- stage K tile transposed: kT[d][j] = K[kt*64 + j][d] ----
    {
      const int j  = lane;        // key index
      const int dw = w * 16;      // this wave covers dims dw..dw+15
      const float* src = kb + (size_t)(kt * kTK + j) * kD + dw;
      float4 a0 = *(const float4*)(src + 0);
      float4 a1 = *(const float4*)(src + 4);
      float4 a2 = *(const float4*)(src + 8);
      float4 a3 = *(const float4*)(src + 12);
      float tmp[16] = {a0.x, a0.y, a0.z, a0.w, a1.x, a1.y, a1.z, a1.w,
                       a2.x, a2.y, a2.z, a2.w, a3.x, a3.y, a3.z, a3.w};
#pragma unroll
      for (int i = 0; i < 16; ++i) kT[dw + i][j] = tmp[i];  // bank=j%32: free
    }
    // ---- stage V tile row-major: vS[j][d] (fully coalesced, b128 writes) ----
    {
      const int jj = tid >> 4;          // 0..15
      const int d4 = (tid & 15) * 4;    // 0,4,..,60
#pragma unroll
      for (int it = 0; it < 4; ++it) {
        const int j = jj + it * 16;
        *(float4*)&vS[j][d4] =
            *(const float4*)(vb + (size_t)(kt * kTK + j) * kD + d4);
      }
    }
    __syncthreads();

#pragma unroll
    for (int g = 0; g < kRowsPerWave / 4; ++g) {
      const int r = row0 + g * 4;
      const float* q0 = qb + (size_t)(r + 0) * kD;
      const float* q1 = qb + (size_t)(r + 1) * kD;
      const float* q2 = qb + (size_t)(r + 2) * kD;
      const float* q3 = qb + (size_t)(r + 3) * kD;

      // ---- QK^T: lane = key j; 1 ds_read shared by 4 rows' fmas ----
      float s0 = 0.f, s1 = 0.f, s2 = 0.f, s3 = 0.f;
#pragma unroll
      for (int d = 0; d < kD; ++d) {
        const float kd = kT[d][lane];
        s0 = fmaf(q0[d], kd, s0);
        s1 = fmaf(q1[d], kd, s1);
        s2 = fmaf(q2[d], kd, s2);
        s3 = fmaf(q3[d], kd, s3);
      }

      // ---- online softmax update per row ----
      auto upd = [&](float s, float& m_r, float& l_r, float& o_r) -> float {
        const float tm    = wave_max64(s);
        const float mn    = fmaxf(m_r, tm);
        const float p     = __expf(s - mn);
        const float ts    = wave_sum64(p);
        const float alpha = __expf(m_r - mn);  // first tile: exp(-inf)=0
        l_r = l_r * alpha + ts;
        o_r = o_r * alpha;
        m_r = mn;
        return p;
      };
      const float p0 = upd(s0, m_i[g * 4 + 0], l_i[g * 4 + 0], o_i[g * 4 + 0]);
      const float p1 = upd(s1, m_i[g * 4 + 1], l_i[g * 4 + 1], o_i[g * 4 + 1]);
      const float p2 = upd(s2, m_i[g * 4 + 2], l_i[g * 4 + 2], o_i[g * 4 + 2]);
      const float p3 = upd(s3, m_i[g * 4 + 3], l_i[g * 4 + 3], o_i[g * 4 + 3]);

      // ---- PV: lane = dim d; p broadcast via v_readlane (SGPR operand) ----
#pragma unroll
      for (int j = 0; j < kTK; ++j) {
        const float vd = vS[j][lane];
        o_i[g * 4 + 0] = fmaf(lane_bcast(p0, j), vd, o_i[g * 4 + 0]);
        o_i[g * 4 + 1] = fmaf(lane_bcast(p1, j), vd, o_i[g * 4 + 1]);
        o_i[g * 4 + 2] = fmaf(lane_bcast(p2, j), vd, o_i[g * 4 + 2]);
        o_i[g * 4 + 3] = fmaf(lane_bcast(p3, j), vd, o_i[g * 4 + 3]);
      }
    }
  }

  // ---- epilogue: out[row][lane] = o / l (coalesced 256B stores per row) ----
#pragma unroll
  for (int i = 0; i < kRowsPerWave; ++i) {
    const int r = row0 + i;
    ob[(size_t)r * kD + lane] = o_i[i] / l_i[i];
  }
}

}  // namespace

extern "C" void kernel_launch(void* const* d_in, const int* in_sizes, int n_in,
                              void* d_out, int out_size, void* d_ws, size_t ws_size,
                              hipStream_t stream) {
  const float* q = (const float*)d_in[0];
  const float* k = (const float*)d_in[1];
  const float* v = (const float*)d_in[2];
  float* out = (float*)d_out;

  dim3 grid(kS / kRowsPerBlock, kB);  // (32, 128) = 4096 blocks
  fa_fp32_kernel<<<grid, kThreads, 0, stream>>>(q, k, v, out);
}

// Round 2
// 226.480 us; speedup vs baseline: 4.8762x; 4.8762x over previous
//
#include <hip/hip_runtime.h>
#include <math.h>

namespace {

typedef _Float16 half8 __attribute__((ext_vector_type(8)));
typedef float floatx4 __attribute__((ext_vector_type(4)));

constexpr int kS   = 1024;
constexpr int kD   = 64;
constexpr int kPad = 72;   // 144 B row stride: 16B-aligned, 2-way banks (free)
constexpr float kLog2e = 1.4426950408889634f;

union H4 { _Float16 h[4]; uint2 u2; };

__device__ __forceinline__ float fast_exp2(float x) {
#if __has_builtin(__builtin_amdgcn_exp2f)
  return __builtin_amdgcn_exp2f(x);
#else
  return exp2f(x);
#endif
}

__device__ __forceinline__ float fast_rcp(float x) {
#if __has_builtin(__builtin_amdgcn_rcpf)
  return __builtin_amdgcn_rcpf(x);
#else
  return 1.0f / x;
#endif
}

__global__ __launch_bounds__(256, 3)
void fa_mfma_kernel(const float* __restrict__ qg, const float* __restrict__ kg,
                    const float* __restrict__ vg, float* __restrict__ og) {
  // All tiles padded to stride 72 halves (144 B).
  __shared__ __align__(16) _Float16 sQh[64][kPad];  // Q hi, pre-scaled by log2e
  __shared__ __align__(16) _Float16 sQl[64][kPad];  // Q lo (split residual)
  __shared__ __align__(16) _Float16 sK [64][kPad];  // K tile, row-major [key][d]
  __shared__ __align__(16) _Float16 sVt[64][kPad];  // V tile, transposed [d][key]
  __shared__ __align__(16) _Float16 sP [64][kPad];  // P, [qrow][key]

  const int tid  = threadIdx.x;
  const int lane = tid & 63;
  const int w    = __builtin_amdgcn_readfirstlane(tid >> 6);
  const int quad = lane >> 4;
  const int r    = lane & 15;

  const int b     = blockIdx.y;
  const int qbase = blockIdx.x * 64;

  const float* qb = qg + (size_t)b * kS * kD;
  const float* kb = kg + (size_t)b * kS * kD;
  const float* vb = vg + (size_t)b * kS * kD;
  float*       ob = og + (size_t)b * kS * kD;

  // ---------- stage Q once: hi/lo f16 split, pre-scaled by log2(e) ----------
  {
    const int row = tid >> 2;          // 0..63
    const int c0  = (tid & 3) * 16;    // 0,16,32,48
    const float4* src = (const float4*)(qb + (size_t)(qbase + row) * kD + c0);
#pragma unroll
    for (int g = 0; g < 4; ++g) {
      float4 f = src[g];
      float xs[4] = {f.x * kLog2e, f.y * kLog2e, f.z * kLog2e, f.w * kLog2e};
      H4 hh, hl;
#pragma unroll
      for (int j = 0; j < 4; ++j) {
        _Float16 h = (_Float16)xs[j];        // RNE v_cvt_f16_f32
        hh.h[j] = h;
        hl.h[j] = (_Float16)(xs[j] - (float)h);
      }
      *(uint2*)&sQh[row][c0 + g * 4] = hh.u2;
      *(uint2*)&sQl[row][c0 + g * 4] = hl.u2;
    }
  }
  __syncthreads();

  // Loop-invariant Q fragments (B-operand: n=lane&15 -> qrow, k=quad*8+j -> d)
  half8 fqh[2], fql[2];
#pragma unroll
  for (int ks = 0; ks < 2; ++ks) {
    fqh[ks] = *(const half8*)&sQh[w * 16 + r][ks * 32 + quad * 8];
    fql[ks] = *(const half8*)&sQl[w * 16 + r][ks * 32 + quad * 8];
  }

  // Online-softmax state; this lane's qrow = w*16 + r (replicated over quads).
  float m_i = -INFINITY, l_i = 0.f;
  floatx4 O[4] = {floatx4{0.f, 0.f, 0.f, 0.f}, floatx4{0.f, 0.f, 0.f, 0.f},
                  floatx4{0.f, 0.f, 0.f, 0.f}, floatx4{0.f, 0.f, 0.f, 0.f}};

  // K/V prefetch registers (one tile ahead).
  const int krow = tid >> 2, kc0 = (tid & 3) * 16;   // K: row-major copy
  const int vkey = tid & 63, vd0 = (tid >> 6) * 16;  // V: transpose copy
  float4 kbuf[4], vbuf[4];
  {
    const float4* ksrc = (const float4*)(kb + (size_t)krow * kD + kc0);
    const float4* vsrc = (const float4*)(vb + (size_t)vkey * kD + vd0);
#pragma unroll
    for (int g = 0; g < 4; ++g) { kbuf[g] = ksrc[g]; vbuf[g] = vsrc[g]; }
  }

  for (int kt = 0; kt < kS / 64; ++kt) {
    __syncthreads();  // previous tile's compute done; LDS K/V free
    // ---- stage K (row-major f16) from prefetch regs ----
#pragma unroll
    for (int g = 0; g < 4; ++g) {
      float t[4] = {kbuf[g].x, kbuf[g].y, kbuf[g].z, kbuf[g].w};
      H4 hk;
#pragma unroll
      for (int j = 0; j < 4; ++j) hk.h[j] = (_Float16)t[j];
      *(uint2*)&sK[krow][kc0 + g * 4] = hk.u2;
    }
    // ---- stage V transposed: sVt[dim][key] (b16 writes, 2-way banks=free) ----
#pragma unroll
    for (int g = 0; g < 4; ++g) {
      float t[4] = {vbuf[g].x, vbuf[g].y, vbuf[g].z, vbuf[g].w};
#pragma unroll
      for (int j = 0; j < 4; ++j) sVt[vd0 + g * 4 + j][vkey] = (_Float16)t[j];
    }
    // ---- prefetch next tile (wraps harmlessly on last iter) ----
    {
      const int ktn = (kt + 1) & 15;
      const float4* ksrc =
          (const float4*)(kb + (size_t)(ktn * 64 + krow) * kD + kc0);
      const float4* vsrc =
          (const float4*)(vb + (size_t)(ktn * 64 + vkey) * kD + vd0);
#pragma unroll
      for (int g = 0; g < 4; ++g) { kbuf[g] = ksrc[g]; vbuf[g] = vsrc[g]; }
    }
    __syncthreads();  // staging visible to all waves

    // ---- S^T = K · Q^T : D[m=key][n=qrow], split-Q two-term MFMA ----
    floatx4 S[4];
#pragma unroll
    for (int mt = 0; mt < 4; ++mt) {
      floatx4 acc = {0.f, 0.f, 0.f, 0.f};
#pragma unroll
      for (int ks = 0; ks < 2; ++ks) {
        half8 fk = *(const half8*)&sK[mt * 16 + r][ks * 32 + quad * 8];
        acc = __builtin_amdgcn_mfma_f32_16x16x32_f16(fk, fqh[ks], acc, 0, 0, 0);
        acc = __builtin_amdgcn_mfma_f32_16x16x32_f16(fk, fql[ks], acc, 0, 0, 0);
      }
      S[mt] = acc;
    }

    // ---- online softmax (scores already in log2 units) ----
    float tm = -INFINITY;
#pragma unroll
    for (int mt = 0; mt < 4; ++mt)
#pragma unroll
      for (int j = 0; j < 4; ++j) tm = fmaxf(tm, S[mt][j]);
    tm = fmaxf(tm, __shfl_xor(tm, 16, 64));
    tm = fmaxf(tm, __shfl_xor(tm, 32, 64));
    const float mn    = fmaxf(m_i, tm);
    const float alpha = fast_exp2(m_i - mn);  // first tile: exp2(-inf)=0
    float p[4][4];
    float rs = 0.f;
#pragma unroll
    for (int mt = 0; mt < 4; ++mt)
#pragma unroll
      for (int j = 0; j < 4; ++j) {
        p[mt][j] = fast_exp2(S[mt][j] - mn);
        rs += p[mt][j];
      }
    rs += __shfl_xor(rs, 16, 64);
    rs += __shfl_xor(rs, 32, 64);
    l_i = l_i * alpha + rs;
    m_i = mn;

    // ---- write P to LDS: sP[qrow][key], 4 consecutive keys -> b64 ----
#pragma unroll
    for (int mt = 0; mt < 4; ++mt) {
      H4 hp;
#pragma unroll
      for (int j = 0; j < 4; ++j) hp.h[j] = (_Float16)p[mt][j];
      *(uint2*)&sP[w * 16 + r][mt * 16 + quad * 4] = hp.u2;
    }

    // ---- rescale O by alpha (O row = quad*4 + j, alpha lives at lane==row) ----
    float a4[4];
#pragma unroll
    for (int j = 0; j < 4; ++j) a4[j] = __shfl(alpha, quad * 4 + j, 64);
#pragma unroll
    for (int nt = 0; nt < 4; ++nt)
#pragma unroll
      for (int j = 0; j < 4; ++j) O[nt][j] *= a4[j];

    // ---- O += P · V  (A=P from LDS, B=V^T rows from sVt) ----
#pragma unroll
    for (int ks = 0; ks < 2; ++ks) {
      half8 fp = *(const half8*)&sP[w * 16 + r][ks * 32 + quad * 8];
#pragma unroll
      for (int nt = 0; nt < 4; ++nt) {
        half8 fv = *(const half8*)&sVt[nt * 16 + r][ks * 32 + quad * 8];
        O[nt] = __builtin_amdgcn_mfma_f32_16x16x32_f16(fp, fv, O[nt], 0, 0, 0);
      }
    }
  }

  // ---- epilogue: out[qrow][dim] = O / l ----
#pragma unroll
  for (int j = 0; j < 4; ++j) {
    const float lrow = __shfl(l_i, quad * 4 + j, 64);
    const float linv = fast_rcp(lrow);
    float* dst = ob + (size_t)(qbase + w * 16 + quad * 4 + j) * kD + r;
#pragma unroll
    for (int nt = 0; nt < 4; ++nt) dst[nt * 16] = O[nt][j] * linv;
  }
}

}  // namespace

extern "C" void kernel_launch(void* const* d_in, const int* in_sizes, int n_in,
                              void* d_out, int out_size, void* d_ws, size_t ws_size,
                              hipStream_t stream) {
  const float* q = (const float*)d_in[0];
  const float* k = (const float*)d_in[1];
  const float* v = (const float*)d_in[2];
  float* out = (float*)d_out;

  dim3 grid(kS / 64, 128);  // (16, 128) = 2048 blocks, 64 q-rows each
  fa_mfma_kernel<<<grid, 256, 0, stream>>>(q, k, v, out);
}

// Round 3
// 202.166 us; speedup vs baseline: 5.4627x; 1.1203x over previous
//
#include <hip/hip_runtime.h>
#include <math.h>

namespace {

typedef _Float16 half8 __attribute__((ext_vector_type(8)));
typedef float floatx4 __attribute__((ext_vector_type(4)));

constexpr int kS   = 1024;
constexpr int kD   = 64;
constexpr int kPad = 72;   // 144 B row stride: 16B-aligned, banks at phase floor
constexpr float kLog2e = 1.4426950408889634f;

union H4 { _Float16 h[4]; uint2 u2; };

__device__ __forceinline__ float fast_exp2(float x) {
#if __has_builtin(__builtin_amdgcn_exp2f)
  return __builtin_amdgcn_exp2f(x);
#else
  return exp2f(x);
#endif
}

__device__ __forceinline__ float fast_rcp(float x) {
#if __has_builtin(__builtin_amdgcn_rcpf)
  return __builtin_amdgcn_rcpf(x);
#else
  return 1.0f / x;
#endif
}

__global__ __launch_bounds__(256, 3)
void fa_mfma_kernel(const float* __restrict__ qg, const float* __restrict__ kg,
                    const float* __restrict__ vg, float* __restrict__ og) {
  // 64 q-rows/wave would double again but blow VGPRs; 32 is the sweet spot.
  __shared__ __align__(16) _Float16 sK [64][kPad];   // K tile [key][d]
  __shared__ __align__(16) _Float16 sVt[64][kPad];   // V^T tile [d][key]
  __shared__ __align__(16) _Float16 sP [128][kPad];  // P [qrow(block)][key]

  const int tid  = threadIdx.x;
  const int lane = tid & 63;
  const int w    = __builtin_amdgcn_readfirstlane(tid >> 6);
  const int quad = lane >> 4;
  const int r    = lane & 15;

  // XCD swizzle: all 8 q-tiles of a batch -> same XCD (i%8 dispatch heuristic).
  const int blk = blockIdx.x;
  const int s   = blk >> 3;
  const int b   = (blk & 7) + 8 * (s & 15);  // batch 0..127
  const int qbase = (s >> 4) * 128;          // q-tile 0..7

  const float* qb = qg + (size_t)b * kS * kD;
  const float* kb = kg + (size_t)b * kS * kD;
  const float* vb = vg + (size_t)b * kS * kD;
  float*       ob = og + (size_t)b * kS * kD;

  // ---- Q fragments direct from global: hi/lo f16 split, pre-scaled log2e ----
  // B-operand layout: n = lane&15 -> qrow-in-group, k = quad*8+j -> dim.
  half8 fqh[2][2], fql[2][2];  // [ntq][ks]
#pragma unroll
  for (int ntq = 0; ntq < 2; ++ntq)
#pragma unroll
    for (int ks = 0; ks < 2; ++ks) {
      const float* src =
          qb + (size_t)(qbase + w * 32 + ntq * 16 + r) * kD + ks * 32 + quad * 8;
      float4 a = ((const float4*)src)[0];
      float4 c = ((const float4*)src)[1];
      float f[8] = {a.x, a.y, a.z, a.w, c.x, c.y, c.z, c.w};
#pragma unroll
      for (int j = 0; j < 8; ++j) {
        float x = f[j] * kLog2e;
        _Float16 h = (_Float16)x;
        fqh[ntq][ks][j] = h;
        fql[ntq][ks][j] = (_Float16)(x - (float)h);
      }
    }

  // Softmax state: lane's 2 q-rows are ntq*16 + r (replicated across quads).
  float m_i[2] = {-INFINITY, -INFINITY}, l_i[2] = {0.f, 0.f};
  // O accum: D[m=qrow][n=dim]; [mtq][nd], row=mtq*16+quad*4+reg, col=nd*16+r.
  floatx4 O[2][4];
#pragma unroll
  for (int a = 0; a < 2; ++a)
#pragma unroll
    for (int c = 0; c < 4; ++c) O[a][c] = floatx4{0.f, 0.f, 0.f, 0.f};

  // K/V prefetch registers (one tile ahead).
  const int krow = tid >> 2, kc0 = (tid & 3) * 16;   // K row-major copy
  const int vkey = tid & 63, vd0 = (tid >> 6) * 16;  // V transpose copy
  float4 kbuf[4], vbuf[4];
  {
    const float4* ksrc = (const float4*)(kb + (size_t)krow * kD + kc0);
    const float4* vsrc = (const float4*)(vb + (size_t)vkey * kD + vd0);
#pragma unroll
    for (int g = 0; g < 4; ++g) { kbuf[g] = ksrc[g]; vbuf[g] = vsrc[g]; }
  }

  for (int kt = 0; kt < kS / 64; ++kt) {
    __syncthreads();  // previous tile's compute done; LDS K/V reusable
    // ---- stage K (row-major f16) ----
#pragma unroll
    for (int g = 0; g < 4; ++g) {
      float t[4] = {kbuf[g].x, kbuf[g].y, kbuf[g].z, kbuf[g].w};
      H4 hk;
#pragma unroll
      for (int j = 0; j < 4; ++j) hk.h[j] = (_Float16)t[j];
      *(uint2*)&sK[krow][kc0 + g * 4] = hk.u2;
    }
    // ---- stage V transposed: sVt[dim][key] ----
#pragma unroll
    for (int g = 0; g < 4; ++g) {
      float t[4] = {vbuf[g].x, vbuf[g].y, vbuf[g].z, vbuf[g].w};
#pragma unroll
      for (int j = 0; j < 4; ++j) sVt[vd0 + g * 4 + j][vkey] = (_Float16)t[j];
    }
    // ---- prefetch next tile ----
    {
      const int ktn = (kt + 1) & 15;
      const float4* ksrc =
          (const float4*)(kb + (size_t)(ktn * 64 + krow) * kD + kc0);
      const float4* vsrc =
          (const float4*)(vb + (size_t)(ktn * 64 + vkey) * kD + vd0);
#pragma unroll
      for (int g = 0; g < 4; ++g) { kbuf[g] = ksrc[g]; vbuf[g] = vsrc[g]; }
    }
    __syncthreads();

    // ---- S^T = K·Q^T: per mt one pair of fk reads feeds BOTH q-groups ----
    floatx4 S[2][4];  // [ntq][mt]; score(key=mt*16+quad*4+reg, qrow=ntq*16+r)
#pragma unroll
    for (int mt = 0; mt < 4; ++mt) {
      half8 fk0 = *(const half8*)&sK[mt * 16 + r][0 * 32 + quad * 8];
      half8 fk1 = *(const half8*)&sK[mt * 16 + r][1 * 32 + quad * 8];
#pragma unroll
      for (int ntq = 0; ntq < 2; ++ntq) {
        floatx4 ah = {0.f, 0.f, 0.f, 0.f}, al = {0.f, 0.f, 0.f, 0.f};
        ah = __builtin_amdgcn_mfma_f32_16x16x32_f16(fk0, fqh[ntq][0], ah, 0, 0, 0);
        ah = __builtin_amdgcn_mfma_f32_16x16x32_f16(fk1, fqh[ntq][1], ah, 0, 0, 0);
        al = __builtin_amdgcn_mfma_f32_16x16x32_f16(fk0, fql[ntq][0], al, 0, 0, 0);
        al = __builtin_amdgcn_mfma_f32_16x16x32_f16(fk1, fql[ntq][1], al, 0, 0, 0);
        S[ntq][mt] = ah + al;
      }
    }

    // ---- online softmax per q-group; pack P to f16 immediately ----
    float alpha[2];
#pragma unroll
    for (int ntq = 0; ntq < 2; ++ntq) {
      float tm = -INFINITY;
#pragma unroll
      for (int mt = 0; mt < 4; ++mt)
#pragma unroll
        for (int j = 0; j < 4; ++j) tm = fmaxf(tm, S[ntq][mt][j]);
      tm = fmaxf(tm, __shfl_xor(tm, 16, 64));
      tm = fmaxf(tm, __shfl_xor(tm, 32, 64));
      const float mn = fmaxf(m_i[ntq], tm);
      alpha[ntq] = fast_exp2(m_i[ntq] - mn);  // first tile: exp2(-inf)=0
      float rs = 0.f;
#pragma unroll
      for (int mt = 0; mt < 4; ++mt) {
        H4 hp;
#pragma unroll
        for (int j = 0; j < 4; ++j) {
          float pj = fast_exp2(S[ntq][mt][j] - mn);
          rs += pj;
          hp.h[j] = (_Float16)pj;
        }
        *(uint2*)&sP[w * 32 + ntq * 16 + r][mt * 16 + quad * 4] = hp.u2;
      }
      rs += __shfl_xor(rs, 16, 64);
      rs += __shfl_xor(rs, 32, 64);
      l_i[ntq] = l_i[ntq] * alpha[ntq] + rs;
      m_i[ntq] = mn;
    }

    // ---- rescale O by alpha (row of O[mtq] = mtq*16 + quad*4 + j) ----
#pragma unroll
    for (int mtq = 0; mtq < 2; ++mtq)
#pragma unroll
      for (int j = 0; j < 4; ++j) {
        const float a = __shfl(alpha[mtq], quad * 4 + j, 64);
#pragma unroll
        for (int nd = 0; nd < 4; ++nd) O[mtq][nd][j] *= a;
      }

    // ---- O += P·V: fv reads shared across both q-row groups ----
#pragma unroll
    for (int ks = 0; ks < 2; ++ks) {
      half8 fp0 = *(const half8*)&sP[w * 32 + 0 * 16 + r][ks * 32 + quad * 8];
      half8 fp1 = *(const half8*)&sP[w * 32 + 1 * 16 + r][ks * 32 + quad * 8];
#pragma unroll
      for (int nd = 0; nd < 4; ++nd) {
        half8 fv = *(const half8*)&sVt[nd * 16 + r][ks * 32 + quad * 8];
        O[0][nd] = __builtin_amdgcn_mfma_f32_16x16x32_f16(fp0, fv, O[0][nd], 0, 0, 0);
        O[1][nd] = __builtin_amdgcn_mfma_f32_16x16x32_f16(fp1, fv, O[1][nd], 0, 0, 0);
      }
    }
  }

  // ---- epilogue: out[qrow][dim] = O / l ----
#pragma unroll
  for (int mtq = 0; mtq < 2; ++mtq)
#pragma unroll
    for (int j = 0; j < 4; ++j) {
      const float lrow = __shfl(l_i[mtq], quad * 4 + j, 64);
      const float linv = fast_rcp(lrow);
      float* dst =
          ob + (size_t)(qbase + w * 32 + mtq * 16 + quad * 4 + j) * kD + r;
#pragma unroll
      for (int nd = 0; nd < 4; ++nd) dst[nd * 16] = O[mtq][nd][j] * linv;
    }
}

}  // namespace

extern "C" void kernel_launch(void* const* d_in, const int* in_sizes, int n_in,
                              void* d_out, int out_size, void* d_ws, size_t ws_size,
                              hipStream_t stream) {
  const float* q = (const float*)d_in[0];
  const float* k = (const float*)d_in[1];
  const float* v = (const float*)d_in[2];
  float* out = (float*)d_out;

  fa_mfma_kernel<<<dim3(1024), 256, 0, stream>>>(q, k, v, out);
}